// Round 1
// baseline (2147.930 us; speedup 1.0000x reference)
//
#include <hip/hip_runtime.h>
#include <cstdint>
#include <cstddef>
#include <math.h>

#define B_   2
#define T_   2048
#define DM   1024
#define NH   16
#define DH   64
#define DC1  384
#define DCC  256
#define DR   32
#define BT   (B_*T_)
#define DQK  96      // DH + DR

// ---------------------------------------------------------------------------
// Generic fp32 tiled GEMM: C[M,N] = A[M,K] @ B[K,N] (row-major).
// 64x64 tile, 16x16 threads, 4x4 microtile, K-tile 16.
// M assumed multiple of 64; N,K guarded where needed (K mult of 16 here).
// ---------------------------------------------------------------------------
__global__ __launch_bounds__(256) void gemm_f32(
    const float* __restrict__ A, const float* __restrict__ Bm,
    float* __restrict__ C, int M, int N, int K) {
  __shared__ float As[16][65];   // [k][m], +1 pad
  __shared__ float Bs[16][65];   // [k][n], +1 pad
  const int bm = blockIdx.y * 64, bn = blockIdx.x * 64;
  const int tx = threadIdx.x, ty = threadIdx.y;
  const int tid = ty * 16 + tx;
  float acc[4][4] = {};
  for (int k0 = 0; k0 < K; k0 += 16) {
    #pragma unroll
    for (int i = 0; i < 4; i++) {
      int idx = i * 256 + tid;
      int am = idx >> 4, ak = idx & 15;
      As[ak][am] = A[(size_t)(bm + am) * K + (k0 + ak)];
      int bn2 = idx & 63, bk = idx >> 6;
      float bv = 0.f;
      if (bn + bn2 < N) bv = Bm[(size_t)(k0 + bk) * N + (bn + bn2)];
      Bs[bk][bn2] = bv;
    }
    __syncthreads();
    #pragma unroll
    for (int k = 0; k < 16; k++) {
      float a0[4], b0[4];
      #pragma unroll
      for (int i = 0; i < 4; i++) a0[i] = As[k][ty*4+i];
      #pragma unroll
      for (int j = 0; j < 4; j++) b0[j] = Bs[k][tx*4+j];
      #pragma unroll
      for (int i = 0; i < 4; i++)
        #pragma unroll
        for (int j = 0; j < 4; j++)
          acc[i][j] = fmaf(a0[i], b0[j], acc[i][j]);
    }
    __syncthreads();
  }
  #pragma unroll
  for (int i = 0; i < 4; i++) {
    int m = bm + ty*4 + i;
    #pragma unroll
    for (int j = 0; j < 4; j++) {
      int n = bn + tx*4 + j;
      if (n < N) C[(size_t)m * N + n] = acc[i][j];
    }
  }
}

// ---------------------------------------------------------------------------
// Assemble: per (row, head) wave -> RoPE + concat + RMS-norm, write q_final /
// k_final in head-major layout [(b*NH+h)][t][96] for coalesced attention.
// Lane l holds dim l (0..63 = content part) and, for l<32, dim 64+l (rope).
// ---------------------------------------------------------------------------
__global__ __launch_bounds__(256) void assemble_qk(
    const float* __restrict__ qs,  // [BT][DM]  q_state (head-major cols)
    const float* __restrict__ qr,  // [BT][NH*DR]
    const float* __restrict__ ks,  // [BT][DM]
    const float* __restrict__ kr,  // [BT][DR]
    float* __restrict__ qf, float* __restrict__ kf) {
  int wid  = (blockIdx.x * blockDim.x + threadIdx.x) >> 6;
  int lane = threadIdx.x & 63;
  int h   = wid & (NH-1);
  int row = wid >> 4;            // 0..BT-1
  int b   = row >> 11;           // /T_
  int t   = row & (T_-1);

  float v0q = qs[(size_t)row*DM + h*DH + lane];
  float v0k = ks[(size_t)row*DM + h*DH + lane];
  float v1q = 0.f, v1k = 0.f;
  if (lane < DR) {
    int j  = lane;
    int jj = j & 15;
    float invf = powf(10000.f, -(float)jj / 16.f);
    float ang  = (float)t * invf;
    float s, c;
    sincosf(ang, &s, &c);
    float qx1 = qr[(size_t)row*(NH*DR) + h*DR + jj];
    float qx2 = qr[(size_t)row*(NH*DR) + h*DR + 16 + jj];
    float kx1 = kr[(size_t)row*DR + jj];
    float kx2 = kr[(size_t)row*DR + 16 + jj];
    if (j < 16) { v1q = qx1*c - qx2*s; v1k = kx1*c - kx2*s; }
    else        { v1q = qx1*s + qx2*c; v1k = kx1*s + kx2*c; }
  }
  float ssq = v0q*v0q + v1q*v1q;
  float ssk = v0k*v0k + v1k*v1k;
  #pragma unroll
  for (int off = 32; off; off >>= 1) {
    ssq += __shfl_xor(ssq, off);
    ssk += __shfl_xor(ssk, off);
  }
  float sq = rsqrtf(ssq / 96.f + 1e-6f);
  float sk = rsqrtf(ssk / 96.f + 1e-6f);
  size_t obase = ((size_t)(b*NH + h) * T_ + t) * DQK;
  qf[obase + lane] = v0q * sq;
  kf[obase + lane] = v0k * sk;
  if (lane < DR) {
    qf[obase + DH + lane] = v1q * sq;
    kf[obase + DH + lane] = v1k * sk;
  }
}

// ---------------------------------------------------------------------------
// Flash-style causal attention. One thread per query; K/V tiles in LDS
// (uniform-address broadcast reads). Online softmax, -1e30 masking.
// Grid: (T/256, B*NH), block 256.
// ---------------------------------------------------------------------------
#define BQ 256
#define BK 64
__global__ __launch_bounds__(256) void flash_attn(
    const float* __restrict__ qf,  // [(b*NH+h)][T][96]
    const float* __restrict__ kf,  // same layout
    const float* __restrict__ vs,  // [b*T+t][NH*DH]  (head-major cols)
    float* __restrict__ ao) {      // [b*T+t][NH*DH]
  __shared__ float Ks[BK * DQK];
  __shared__ float Vs[BK * DH];
  const int hb = blockIdx.y;          // 0..B*NH-1
  const int b  = hb >> 4, h = hb & (NH-1);
  const int tq = blockIdx.x * BQ + threadIdx.x;
  const float scale = 0.1020620726159658f;  // 1/sqrt(96)

  float q[DQK];
  {
    const float4* qp = (const float4*)(qf + ((size_t)hb * T_ + tq) * DQK);
    #pragma unroll
    for (int i = 0; i < DQK/4; i++) {
      float4 v = qp[i];
      q[4*i] = v.x; q[4*i+1] = v.y; q[4*i+2] = v.z; q[4*i+3] = v.w;
    }
  }
  float m = -1e30f, l = 0.f;
  float o[DH];
  #pragma unroll
  for (int d = 0; d < DH; d++) o[d] = 0.f;

  const int kmax = blockIdx.x * BQ + BQ;   // exclusive key bound for block
  for (int k0 = 0; k0 < kmax; k0 += BK) {
    __syncthreads();
    {
      const float* kg = kf + ((size_t)hb * T_ + k0) * DQK;
      for (int i = threadIdx.x; i < BK * DQK; i += 256) Ks[i] = kg[i];
      const float* vg = vs + (size_t)(b * T_ + k0) * DM + h * DH;
      for (int i = threadIdx.x; i < BK * DH; i += 256) {
        int kk = i >> 6, d = i & 63;
        Vs[i] = vg[(size_t)kk * DM + d];
      }
    }
    __syncthreads();
    #pragma unroll 1
    for (int k = 0; k < BK; k++) {
      const float4* kp = (const float4*)(Ks + k * DQK);
      float a0 = 0.f, a1 = 0.f, a2 = 0.f, a3 = 0.f;
      #pragma unroll
      for (int i = 0; i < DQK/4; i++) {
        float4 v = kp[i];
        a0 = fmaf(q[4*i],   v.x, a0);
        a1 = fmaf(q[4*i+1], v.y, a1);
        a2 = fmaf(q[4*i+2], v.z, a2);
        a3 = fmaf(q[4*i+3], v.w, a3);
      }
      float s = (a0 + a1 + a2 + a3) * scale;
      if (k0 + k > tq) s = -1e30f;
      float mn = fmaxf(m, s);
      float c  = __expf(m - mn);
      float p  = __expf(s - mn);
      l = l * c + p;
      const float4* vp = (const float4*)(Vs + k * DH);
      #pragma unroll
      for (int i = 0; i < DH/4; i++) {
        float4 v = vp[i];
        o[4*i]   = fmaf(p, v.x, o[4*i]   * c);
        o[4*i+1] = fmaf(p, v.y, o[4*i+1] * c);
        o[4*i+2] = fmaf(p, v.z, o[4*i+2] * c);
        o[4*i+3] = fmaf(p, v.w, o[4*i+3] * c);
      }
      m = mn;
    }
  }
  float inv = 1.f / l;
  float4* op = (float4*)(ao + (size_t)(b * T_ + tq) * DM + h * DH);
  #pragma unroll
  for (int i = 0; i < DH/4; i++) {
    float4 v;
    v.x = o[4*i]   * inv; v.y = o[4*i+1] * inv;
    v.z = o[4*i+2] * inv; v.w = o[4*i+3] * inv;
    op[i] = v;
  }
}

// ---------------------------------------------------------------------------
extern "C" void kernel_launch(void* const* d_in, const int* in_sizes, int n_in,
                              void* d_out, int out_size, void* d_ws, size_t ws_size,
                              hipStream_t stream) {
  const float* x     = (const float*)d_in[0];
  const float* w_dq  = (const float*)d_in[1];
  const float* w_uq  = (const float*)d_in[2];
  const float* w_rq  = (const float*)d_in[3];
  const float* w_dkv = (const float*)d_in[4];
  const float* w_rk  = (const float*)d_in[5];
  const float* w_uk  = (const float*)d_in[6];
  const float* w_uv  = (const float*)d_in[7];
  const float* w_o   = (const float*)d_in[8];
  // d_in[9] = mask: causal, hard-coded in flash_attn.
  float* out = (float*)d_out;

  float* ws  = (float*)d_ws;
  float* c_q  = ws;                          // BT*DC1
  float* c_kv = c_q  + (size_t)BT*DC1;       // BT*DCC
  float* kr   = c_kv + (size_t)BT*DCC;       // BT*DR
  float* qs   = kr   + (size_t)BT*DR;        // BT*DM
  float* qr   = qs   + (size_t)BT*DM;        // BT*NH*DR
  float* ks   = qr   + (size_t)BT*NH*DR;     // BT*DM
  float* vs   = ks   + (size_t)BT*DM;        // BT*DM
  float* qf   = vs   + (size_t)BT*DM;        // B*NH*T*DQK
  float* kf   = qf   + (size_t)B_*NH*T_*DQK; // B*NH*T*DQK
  // attention output aliases the (dead by then) c_q/c_kv/kr + head of qs:
  float* ao   = ws;                          // BT*DM

  dim3 blk(16, 16);
  auto grd = [](int N, int M) { return dim3((N + 63) / 64, (M + 63) / 64); };

  // Phase A: projections
  gemm_f32<<<grd(DC1, BT),  blk, 0, stream>>>(x,    w_dq,  c_q,  BT, DC1,   DM);
  gemm_f32<<<grd(DCC, BT),  blk, 0, stream>>>(x,    w_dkv, c_kv, BT, DCC,   DM);
  gemm_f32<<<grd(DR,  BT),  blk, 0, stream>>>(x,    w_rk,  kr,   BT, DR,    DM);
  gemm_f32<<<grd(DM,  BT),  blk, 0, stream>>>(c_q,  w_uq,  qs,   BT, DM,    DC1);
  gemm_f32<<<grd(NH*DR, BT),blk, 0, stream>>>(c_q,  w_rq,  qr,   BT, NH*DR, DC1);
  gemm_f32<<<grd(DM,  BT),  blk, 0, stream>>>(c_kv, w_uk,  ks,   BT, DM,    DCC);
  gemm_f32<<<grd(DM,  BT),  blk, 0, stream>>>(c_kv, w_uv,  vs,   BT, DM,    DCC);

  // Phase B: rope + concat + rmsnorm + head-major transpose
  assemble_qk<<<(BT * NH) / 4, 256, 0, stream>>>(qs, qr, ks, kr, qf, kf);

  // Phase C: causal flash attention
  flash_attn<<<dim3(T_ / BQ, B_ * NH), 256, 0, stream>>>(qf, kf, vs, ao);

  // Phase D: output projection
  gemm_f32<<<grd(DM, BT), blk, 0, stream>>>(ao, w_o, out, BT, DM, DM);
}

// Round 2
// 1125.687 us; speedup vs baseline: 1.9081x; 1.9081x over previous
//
#include <hip/hip_runtime.h>
#include <cstdint>
#include <cstddef>
#include <math.h>

#define B_   2
#define T_   2048
#define DM   1024
#define NH   16
#define DH   64
#define DC1  384
#define DCC  256
#define DR   32
#define BT   (B_*T_)
#define DQK  96      // DH + DR

typedef __bf16 bf16x8 __attribute__((ext_vector_type(8)));
typedef float  f32x4  __attribute__((ext_vector_type(4)));
#define MFMA16(a,b,c) __builtin_amdgcn_mfma_f32_16x16x32_bf16((a),(b),(c),0,0,0)

// ---------------------------------------------------------------------------
// Generic fp32 tiled GEMM: C[M,N] = A[M,K] @ B[K,N] (row-major).
// ---------------------------------------------------------------------------
__global__ __launch_bounds__(256) void gemm_f32(
    const float* __restrict__ A, const float* __restrict__ Bm,
    float* __restrict__ C, int M, int N, int K) {
  __shared__ float As[16][65];
  __shared__ float Bs[16][65];
  const int bm = blockIdx.y * 64, bn = blockIdx.x * 64;
  const int tx = threadIdx.x, ty = threadIdx.y;
  const int tid = ty * 16 + tx;
  float acc[4][4] = {};
  for (int k0 = 0; k0 < K; k0 += 16) {
    #pragma unroll
    for (int i = 0; i < 4; i++) {
      int idx = i * 256 + tid;
      int am = idx >> 4, ak = idx & 15;
      As[ak][am] = A[(size_t)(bm + am) * K + (k0 + ak)];
      int bn2 = idx & 63, bk = idx >> 6;
      float bv = 0.f;
      if (bn + bn2 < N) bv = Bm[(size_t)(k0 + bk) * N + (bn + bn2)];
      Bs[bk][bn2] = bv;
    }
    __syncthreads();
    #pragma unroll
    for (int k = 0; k < 16; k++) {
      float a0[4], b0[4];
      #pragma unroll
      for (int i = 0; i < 4; i++) a0[i] = As[k][ty*4+i];
      #pragma unroll
      for (int j = 0; j < 4; j++) b0[j] = Bs[k][tx*4+j];
      #pragma unroll
      for (int i = 0; i < 4; i++)
        #pragma unroll
        for (int j = 0; j < 4; j++)
          acc[i][j] = fmaf(a0[i], b0[j], acc[i][j]);
    }
    __syncthreads();
  }
  #pragma unroll
  for (int i = 0; i < 4; i++) {
    int m = bm + ty*4 + i;
    #pragma unroll
    for (int j = 0; j < 4; j++) {
      int n = bn + tx*4 + j;
      if (n < N) C[(size_t)m * N + n] = acc[i][j];
    }
  }
}

// ---------------------------------------------------------------------------
// Assemble: per (row, head) wave -> RoPE + concat + RMS-norm.
// Outputs bf16: qb/kb [(b*16+h)][t][96], vb [(b*16+h)][t][64].
// ---------------------------------------------------------------------------
__global__ __launch_bounds__(256) void assemble_qk(
    const float* __restrict__ qs, const float* __restrict__ qr,
    const float* __restrict__ ks, const float* __restrict__ kr,
    const float* __restrict__ vs,
    __bf16* __restrict__ qb, __bf16* __restrict__ kb,
    __bf16* __restrict__ vb) {
  int wid  = (blockIdx.x * blockDim.x + threadIdx.x) >> 6;
  int lane = threadIdx.x & 63;
  int h   = wid & (NH-1);
  int row = wid >> 4;
  int b   = row >> 11;
  int t   = row & (T_-1);

  float v0q = qs[(size_t)row*DM + h*DH + lane];
  float v0k = ks[(size_t)row*DM + h*DH + lane];
  float vv  = vs[(size_t)row*DM + h*DH + lane];
  float v1q = 0.f, v1k = 0.f;
  if (lane < DR) {
    int j  = lane;
    int jj = j & 15;
    float invf = powf(10000.f, -(float)jj / 16.f);
    float ang  = (float)t * invf;
    float s, c;
    sincosf(ang, &s, &c);
    float qx1 = qr[(size_t)row*(NH*DR) + h*DR + jj];
    float qx2 = qr[(size_t)row*(NH*DR) + h*DR + 16 + jj];
    float kx1 = kr[(size_t)row*DR + jj];
    float kx2 = kr[(size_t)row*DR + 16 + jj];
    if (j < 16) { v1q = qx1*c - qx2*s; v1k = kx1*c - kx2*s; }
    else        { v1q = qx1*s + qx2*c; v1k = kx1*s + kx2*c; }
  }
  float ssq = v0q*v0q + v1q*v1q;
  float ssk = v0k*v0k + v1k*v1k;
  #pragma unroll
  for (int off = 32; off; off >>= 1) {
    ssq += __shfl_xor(ssq, off);
    ssk += __shfl_xor(ssk, off);
  }
  float sq = rsqrtf(ssq / 96.f + 1e-6f);
  float sk = rsqrtf(ssk / 96.f + 1e-6f);
  size_t hbT = (size_t)(b*NH + h) * T_ + t;
  size_t obase = hbT * DQK;
  qb[obase + lane] = (__bf16)(v0q * sq);
  kb[obase + lane] = (__bf16)(v0k * sk);
  vb[hbT * DH + lane] = (__bf16)vv;
  if (lane < DR) {
    qb[obase + DH + lane] = (__bf16)(v1q * sq);
    kb[obase + DH + lane] = (__bf16)(v1k * sk);
  }
}

// ---------------------------------------------------------------------------
// MFMA bf16 flash attention (causal). Block = 64 queries (4 waves x 16q),
// K/V tiles of 32 keys staged in LDS. 16x16x32 MFMA; P via LDS round-trip.
// Grid: (32 q-tiles [descending], 32 hb). ao is fp32 [b*T+t][DM].
// ---------------------------------------------------------------------------
#define KS_STR 104   // K LDS row stride (bf16): 2-way bank, 16B aligned
#define VT_STR 40    // V^T LDS row stride
#define P_STR  40    // P LDS row stride
__global__ __launch_bounds__(256) void flash_mfma(
    const __bf16* __restrict__ qg, const __bf16* __restrict__ kg,
    const __bf16* __restrict__ vg, float* __restrict__ ao) {
  __shared__ __align__(16) __bf16 Ksh[32 * KS_STR];
  __shared__ __align__(16) __bf16 Vth[64 * VT_STR];
  __shared__ __align__(16) __bf16 Psh[4 * 16 * P_STR];

  const int hb = blockIdx.y;
  const int bb = hb >> 4, h = hb & 15;
  const int q0 = T_ - 64 - 64 * blockIdx.x;   // heavy tiles first
  const int w  = threadIdx.x >> 6;
  const int l  = threadIdx.x & 63;
  const int g  = l >> 4;        // 0..3
  const int ln = l & 15;        // 0..15
  const int qw = q0 + w * 16;   // wave's first query
  const float scale = 0.10206207261596577f;  // 1/sqrt(96)
  const size_t hbT = (size_t)hb * T_;

  // Q fragments (A-operand): lane holds Q[m=ln][k=s*32+g*8+j]
  bf16x8 qfrag[3];
  #pragma unroll
  for (int s = 0; s < 3; s++)
    qfrag[s] = *(const bf16x8*)(qg + (hbT + qw + ln) * DQK + s*32 + g*8);

  f32x4 oacc[4];
  #pragma unroll
  for (int t = 0; t < 4; t++) oacc[t] = (f32x4){0.f,0.f,0.f,0.f};
  float m_run[4] = {-1e30f,-1e30f,-1e30f,-1e30f};
  float l_run[4] = {0.f,0.f,0.f,0.f};

  __bf16* Pw = Psh + w * 16 * P_STR;
  const int kmax = q0 + 64;

  for (int k0 = 0; k0 < kmax; k0 += 32) {
    __syncthreads();
    // stage K tile [32 keys][96 dims]
    #pragma unroll
    for (int it = 0; it < 2; it++) {
      int c = threadIdx.x + it * 256;
      if (c < 384) {
        int row = c / 12, cc = c % 12;
        bf16x8 kv = *(const bf16x8*)(kg + (hbT + k0 + row) * DQK + cc*8);
        *(bf16x8*)(Ksh + row * KS_STR + cc*8) = kv;
      }
    }
    // stage V tile transposed [64 dims][32 keys]
    {
      int key = threadIdx.x & 31, d0 = (threadIdx.x >> 5) * 8;
      bf16x8 vv = *(const bf16x8*)(vg + (hbT + k0 + key) * DH + d0);
      #pragma unroll
      for (int j = 0; j < 8; j++) Vth[(d0 + j) * VT_STR + key] = vv[j];
    }
    __syncthreads();

    if (k0 <= qw + 15) {   // wave-uniform: skip fully masked tiles
      // S = Q K^T : two 16-key subtiles
      f32x4 s0 = (f32x4){0.f,0.f,0.f,0.f};
      f32x4 s1 = (f32x4){0.f,0.f,0.f,0.f};
      #pragma unroll
      for (int s = 0; s < 3; s++) {
        bf16x8 kf0 = *(const bf16x8*)(Ksh + ln * KS_STR + s*32 + g*8);
        bf16x8 kf1 = *(const bf16x8*)(Ksh + (ln + 16) * KS_STR + s*32 + g*8);
        s0 = MFMA16(qfrag[s], kf0, s0);
        s1 = MFMA16(qfrag[s], kf1, s1);
      }
      // online softmax: C layout row = g*4+r (query), col = ln (key)
      float cfac[4];
      #pragma unroll
      for (int r = 0; r < 4; r++) {
        int q = qw + g*4 + r;
        float a = s0[r] * scale; if (k0 + ln > q)       a = -1e30f;
        float b = s1[r] * scale; if (k0 + 16 + ln > q)  b = -1e30f;
        float mx = fmaxf(a, b);
        mx = fmaxf(mx, __shfl_xor(mx, 1));
        mx = fmaxf(mx, __shfl_xor(mx, 2));
        mx = fmaxf(mx, __shfl_xor(mx, 4));
        mx = fmaxf(mx, __shfl_xor(mx, 8));
        float mn = fmaxf(m_run[r], mx);
        float pa = __expf(a - mn), pb = __expf(b - mn);
        float cs = __expf(m_run[r] - mn);
        float rs = pa + pb;
        rs += __shfl_xor(rs, 1);
        rs += __shfl_xor(rs, 2);
        rs += __shfl_xor(rs, 4);
        rs += __shfl_xor(rs, 8);
        l_run[r] = l_run[r] * cs + rs;
        m_run[r] = mn;
        cfac[r]  = cs;
        Pw[(g*4 + r) * P_STR + ln]      = (__bf16)pa;
        Pw[(g*4 + r) * P_STR + 16 + ln] = (__bf16)pb;
      }
      // P as A-operand (k = 32 keys), V^T rows as B-operand
      bf16x8 pfrag = *(const bf16x8*)(Pw + ln * P_STR + g*8);
      #pragma unroll
      for (int t = 0; t < 4; t++) {
        bf16x8 vf = *(const bf16x8*)(Vth + (16*t + ln) * VT_STR + g*8);
        f32x4 o = oacc[t];
        o[0] *= cfac[0]; o[1] *= cfac[1]; o[2] *= cfac[2]; o[3] *= cfac[3];
        oacc[t] = MFMA16(pfrag, vf, o);
      }
    }
  }

  float inv[4];
  #pragma unroll
  for (int r = 0; r < 4; r++) inv[r] = 1.f / l_run[r];
  #pragma unroll
  for (int t = 0; t < 4; t++)
    #pragma unroll
    for (int r = 0; r < 4; r++) {
      int q = qw + g*4 + r;
      ao[(size_t)(bb * T_ + q) * DM + h * DH + 16*t + ln] = oacc[t][r] * inv[r];
    }
}

// ---------------------------------------------------------------------------
extern "C" void kernel_launch(void* const* d_in, const int* in_sizes, int n_in,
                              void* d_out, int out_size, void* d_ws, size_t ws_size,
                              hipStream_t stream) {
  const float* x     = (const float*)d_in[0];
  const float* w_dq  = (const float*)d_in[1];
  const float* w_uq  = (const float*)d_in[2];
  const float* w_rq  = (const float*)d_in[3];
  const float* w_dkv = (const float*)d_in[4];
  const float* w_rk  = (const float*)d_in[5];
  const float* w_uk  = (const float*)d_in[6];
  const float* w_uv  = (const float*)d_in[7];
  const float* w_o   = (const float*)d_in[8];
  float* out = (float*)d_out;

  float* ws   = (float*)d_ws;
  float* c_q  = ws;
  float* c_kv = c_q  + (size_t)BT*DC1;
  float* kr   = c_kv + (size_t)BT*DCC;
  float* qs   = kr   + (size_t)BT*DR;
  float* qr   = qs   + (size_t)BT*DM;
  float* ks   = qr   + (size_t)BT*NH*DR;
  float* vs   = ks   + (size_t)BT*DM;
  __bf16* qb  = (__bf16*)(vs + (size_t)BT*DM);
  __bf16* kb  = qb + (size_t)B_*NH*T_*DQK;
  __bf16* vb  = kb + (size_t)B_*NH*T_*DQK;
  float* ao   = ws;   // aliases c_q/c_kv/kr/qs — all dead by flash time

  dim3 blk(16, 16);
  auto grd = [](int N, int M) { return dim3((N + 63) / 64, (M + 63) / 64); };

  // Phase A: projections (fp32)
  gemm_f32<<<grd(DC1, BT),  blk, 0, stream>>>(x,    w_dq,  c_q,  BT, DC1,   DM);
  gemm_f32<<<grd(DCC, BT),  blk, 0, stream>>>(x,    w_dkv, c_kv, BT, DCC,   DM);
  gemm_f32<<<grd(DR,  BT),  blk, 0, stream>>>(x,    w_rk,  kr,   BT, DR,    DM);
  gemm_f32<<<grd(DM,  BT),  blk, 0, stream>>>(c_q,  w_uq,  qs,   BT, DM,    DC1);
  gemm_f32<<<grd(NH*DR, BT),blk, 0, stream>>>(c_q,  w_rq,  qr,   BT, NH*DR, DC1);
  gemm_f32<<<grd(DM,  BT),  blk, 0, stream>>>(c_kv, w_uk,  ks,   BT, DM,    DCC);
  gemm_f32<<<grd(DM,  BT),  blk, 0, stream>>>(c_kv, w_uv,  vs,   BT, DM,    DCC);

  // Phase B: rope + concat + rmsnorm + bf16 head-major layouts
  assemble_qk<<<(BT * NH) / 4, 256, 0, stream>>>(qs, qr, ks, kr, vs, qb, kb, vb);

  // Phase C: causal MFMA flash attention
  flash_mfma<<<dim3(T_ / 64, B_ * NH), 256, 0, stream>>>(qb, kb, vb, ao);

  // Phase D: output projection (fp32)
  gemm_f32<<<grd(DM, BT), blk, 0, stream>>>(ao, w_o, out, BT, DM, DM);
}

// Round 3
// 408.264 us; speedup vs baseline: 5.2611x; 2.7573x over previous
//
#include <hip/hip_runtime.h>
#include <cstdint>
#include <cstddef>
#include <math.h>

#define B_   2
#define T_   2048
#define DM   1024
#define NH   16
#define DH   64
#define DC1  384
#define DCC  256
#define DR   32
#define BT   (B_*T_)
#define DQK  96      // DH + DR

typedef __bf16 bf16x8 __attribute__((ext_vector_type(8)));
typedef __bf16 bf16x4 __attribute__((ext_vector_type(4)));
typedef float  f32x4  __attribute__((ext_vector_type(4)));
#define MFMA16(a,b,c) __builtin_amdgcn_mfma_f32_16x16x32_bf16((a),(b),(c),0,0,0)

__device__ __forceinline__ void gld16(const __bf16* g, __bf16* l) {
  __builtin_amdgcn_global_load_lds(
      (const __attribute__((address_space(1))) void*)g,
      (__attribute__((address_space(3))) void*)l, 16, 0, 0);
}

// ---------------------------------------------------------------------------
// bf16 MFMA GEMM: C[M,N] = A[M,K] @ Bt[N,K]^T.  (m97 structure)
// 128x128 tile, BK=32, 256 threads = 4 waves (2x2), each wave 4x4 MFMA grid.
// A row-major with stride lda; Bt row-major [N][K] (pre-transposed weights).
// ---------------------------------------------------------------------------
template<typename CT>
__global__ __launch_bounds__(256) void gemm_mfma(
    const __bf16* __restrict__ A, int lda,
    const __bf16* __restrict__ Bt, int ldb, int Nvalid,
    CT* __restrict__ C, int ldc, int K) {
  __shared__ __align__(16) __bf16 As[128 * 32];
  __shared__ __align__(16) __bf16 Bs[128 * 32];
  const int m0 = blockIdx.y * 128, n0 = blockIdx.x * 128;
  const int tid = threadIdx.x;
  const int w = tid >> 6, l = tid & 63;
  const int g = l >> 4, ln = l & 15;
  const int wm = w >> 1, wn = w & 1;

  // staging: 512 slots of 16B per matrix; wave w covers slots [w*128, w*128+128)
  const int slot0 = (w * 2 + 0) * 64 + l;
  const int slot1 = (w * 2 + 1) * 64 + l;
  const __bf16* ga0 = A + (size_t)(m0 + (slot0 >> 2)) * lda + (slot0 & 3) * 8;
  const __bf16* ga1 = A + (size_t)(m0 + (slot1 >> 2)) * lda + (slot1 & 3) * 8;
  int bn0 = n0 + (slot0 >> 2); if (bn0 >= Nvalid) bn0 = Nvalid - 1;
  int bn1 = n0 + (slot1 >> 2); if (bn1 >= Nvalid) bn1 = Nvalid - 1;
  const __bf16* gb0 = Bt + (size_t)bn0 * ldb + (slot0 & 3) * 8;
  const __bf16* gb1 = Bt + (size_t)bn1 * ldb + (slot1 & 3) * 8;
  __bf16* la0 = As + (w * 2 + 0) * 512;
  __bf16* la1 = As + (w * 2 + 1) * 512;
  __bf16* lb0 = Bs + (w * 2 + 0) * 512;
  __bf16* lb1 = Bs + (w * 2 + 1) * 512;

  f32x4 acc[4][4];
  #pragma unroll
  for (int i = 0; i < 4; i++)
    #pragma unroll
    for (int j = 0; j < 4; j++) acc[i][j] = (f32x4){0.f, 0.f, 0.f, 0.f};

  for (int k0 = 0; k0 < K; k0 += 32) {
    gld16(ga0 + k0, la0);
    gld16(ga1 + k0, la1);
    gld16(gb0 + k0, lb0);
    gld16(gb1 + k0, lb1);
    __syncthreads();
    bf16x8 af[4], bfr[4];
    #pragma unroll
    for (int mt = 0; mt < 4; mt++)
      af[mt] = *(const bf16x8*)(As + (wm * 64 + mt * 16 + ln) * 32 + g * 8);
    #pragma unroll
    for (int nt = 0; nt < 4; nt++)
      bfr[nt] = *(const bf16x8*)(Bs + (wn * 64 + nt * 16 + ln) * 32 + g * 8);
    #pragma unroll
    for (int mt = 0; mt < 4; mt++)
      #pragma unroll
      for (int nt = 0; nt < 4; nt++)
        acc[mt][nt] = MFMA16(af[mt], bfr[nt], acc[mt][nt]);
    __syncthreads();
  }

  #pragma unroll
  for (int mt = 0; mt < 4; mt++)
    #pragma unroll
    for (int r = 0; r < 4; r++) {
      int m = m0 + wm * 64 + mt * 16 + g * 4 + r;
      #pragma unroll
      for (int nt = 0; nt < 4; nt++) {
        int n = n0 + wn * 64 + nt * 16 + ln;
        if (n < Nvalid) C[(size_t)m * ldc + n] = (CT)acc[mt][nt][r];
      }
    }
}

// ---------------------------------------------------------------------------
// Weight prep: fp32 [K,N] -> bf16 transposed [N,K].  K,N multiples of 32.
// ---------------------------------------------------------------------------
__global__ __launch_bounds__(256) void transpose_cast(
    const float* __restrict__ src, __bf16* __restrict__ dst, int K, int N) {
  __shared__ float t[32][33];
  const int ks = blockIdx.x * 32, ns = blockIdx.y * 32;
  const int tx = threadIdx.x, ty = threadIdx.y;
  #pragma unroll
  for (int i = 0; i < 4; i++)
    t[ty + i * 8][tx] = src[(size_t)(ks + ty + i * 8) * N + ns + tx];
  __syncthreads();
  #pragma unroll
  for (int i = 0; i < 4; i++)
    dst[(size_t)(ns + ty + i * 8) * K + ks + tx] = (__bf16)t[tx][ty + i * 8];
}

__global__ __launch_bounds__(256) void cast_f32_bf16(
    const float* __restrict__ src, __bf16* __restrict__ dst) {
  int i = (blockIdx.x * 256 + threadIdx.x) * 4;
  float4 v = *(const float4*)(src + i);
  bf16x4 o = { (__bf16)v.x, (__bf16)v.y, (__bf16)v.z, (__bf16)v.w };
  *(bf16x4*)(dst + i) = o;
}

// ---------------------------------------------------------------------------
// Assemble: per (row, head) wave -> RoPE + concat + RMS-norm (fp32 math on
// bf16 inputs). Outputs bf16 qb/kb [(b*16+h)][t][96], vb [..][t][64].
// ---------------------------------------------------------------------------
__global__ __launch_bounds__(256) void assemble_qk(
    const __bf16* __restrict__ qsqr,  // [BT][1536]: qs | qr
    const __bf16* __restrict__ kv,    // [BT][2048]: ks | vs
    const __bf16* __restrict__ cqkr,  // [BT][672]: kr at cols 640..671
    __bf16* __restrict__ qb, __bf16* __restrict__ kb,
    __bf16* __restrict__ vb) {
  int wid  = (blockIdx.x * blockDim.x + threadIdx.x) >> 6;
  int lane = threadIdx.x & 63;
  int h   = wid & (NH - 1);
  int row = wid >> 4;
  int b   = row >> 11;
  int t   = row & (T_ - 1);

  float v0q = (float)qsqr[(size_t)row * 1536 + h * DH + lane];
  float v0k = (float)kv[(size_t)row * 2048 + h * DH + lane];
  float vv  = (float)kv[(size_t)row * 2048 + 1024 + h * DH + lane];
  float v1q = 0.f, v1k = 0.f;
  if (lane < DR) {
    int j  = lane;
    int jj = j & 15;
    float invf = powf(10000.f, -(float)jj / 16.f);
    float ang  = (float)t * invf;
    float s, c;
    sincosf(ang, &s, &c);
    float qx1 = (float)qsqr[(size_t)row * 1536 + 1024 + h * DR + jj];
    float qx2 = (float)qsqr[(size_t)row * 1536 + 1024 + h * DR + 16 + jj];
    float kx1 = (float)cqkr[(size_t)row * 672 + 640 + jj];
    float kx2 = (float)cqkr[(size_t)row * 672 + 640 + 16 + jj];
    if (j < 16) { v1q = qx1 * c - qx2 * s; v1k = kx1 * c - kx2 * s; }
    else        { v1q = qx1 * s + qx2 * c; v1k = kx1 * s + kx2 * c; }
  }
  float ssq = v0q * v0q + v1q * v1q;
  float ssk = v0k * v0k + v1k * v1k;
  #pragma unroll
  for (int off = 32; off; off >>= 1) {
    ssq += __shfl_xor(ssq, off);
    ssk += __shfl_xor(ssk, off);
  }
  float sq = rsqrtf(ssq / 96.f + 1e-6f);
  float sk = rsqrtf(ssk / 96.f + 1e-6f);
  size_t hbT = (size_t)(b * NH + h) * T_ + t;
  size_t obase = hbT * DQK;
  qb[obase + lane] = (__bf16)(v0q * sq);
  kb[obase + lane] = (__bf16)(v0k * sk);
  vb[hbT * DH + lane] = (__bf16)vv;
  if (lane < DR) {
    qb[obase + DH + lane] = (__bf16)(v1q * sq);
    kb[obase + DH + lane] = (__bf16)(v1k * sk);
  }
}

// ---------------------------------------------------------------------------
// MFMA bf16 flash attention (causal), as round 2; output now bf16.
// ---------------------------------------------------------------------------
#define KS_STR 104
#define VT_STR 40
#define P_STR  40
__global__ __launch_bounds__(256) void flash_mfma(
    const __bf16* __restrict__ qg, const __bf16* __restrict__ kg,
    const __bf16* __restrict__ vg, __bf16* __restrict__ ao) {
  __shared__ __align__(16) __bf16 Ksh[32 * KS_STR];
  __shared__ __align__(16) __bf16 Vth[64 * VT_STR];
  __shared__ __align__(16) __bf16 Psh[4 * 16 * P_STR];

  const int hb = blockIdx.y;
  const int bb = hb >> 4, h = hb & 15;
  const int q0 = T_ - 64 - 64 * blockIdx.x;
  const int w  = threadIdx.x >> 6;
  const int l  = threadIdx.x & 63;
  const int g  = l >> 4;
  const int ln = l & 15;
  const int qw = q0 + w * 16;
  const float scale = 0.10206207261596577f;
  const size_t hbT = (size_t)hb * T_;

  bf16x8 qfrag[3];
  #pragma unroll
  for (int s = 0; s < 3; s++)
    qfrag[s] = *(const bf16x8*)(qg + (hbT + qw + ln) * DQK + s * 32 + g * 8);

  f32x4 oacc[4];
  #pragma unroll
  for (int t = 0; t < 4; t++) oacc[t] = (f32x4){0.f, 0.f, 0.f, 0.f};
  float m_run[4] = {-1e30f, -1e30f, -1e30f, -1e30f};
  float l_run[4] = {0.f, 0.f, 0.f, 0.f};

  __bf16* Pw = Psh + w * 16 * P_STR;
  const int kmax = q0 + 64;

  for (int k0 = 0; k0 < kmax; k0 += 32) {
    __syncthreads();
    #pragma unroll
    for (int it = 0; it < 2; it++) {
      int c = threadIdx.x + it * 256;
      if (c < 384) {
        int row = c / 12, cc = c % 12;
        bf16x8 kvv = *(const bf16x8*)(kg + (hbT + k0 + row) * DQK + cc * 8);
        *(bf16x8*)(Ksh + row * KS_STR + cc * 8) = kvv;
      }
    }
    {
      int key = threadIdx.x & 31, d0 = (threadIdx.x >> 5) * 8;
      bf16x8 vv = *(const bf16x8*)(vg + (hbT + k0 + key) * DH + d0);
      #pragma unroll
      for (int j = 0; j < 8; j++) Vth[(d0 + j) * VT_STR + key] = vv[j];
    }
    __syncthreads();

    if (k0 <= qw + 15) {
      f32x4 s0 = (f32x4){0.f, 0.f, 0.f, 0.f};
      f32x4 s1 = (f32x4){0.f, 0.f, 0.f, 0.f};
      #pragma unroll
      for (int s = 0; s < 3; s++) {
        bf16x8 kf0 = *(const bf16x8*)(Ksh + ln * KS_STR + s * 32 + g * 8);
        bf16x8 kf1 = *(const bf16x8*)(Ksh + (ln + 16) * KS_STR + s * 32 + g * 8);
        s0 = MFMA16(qfrag[s], kf0, s0);
        s1 = MFMA16(qfrag[s], kf1, s1);
      }
      float cfac[4];
      #pragma unroll
      for (int r = 0; r < 4; r++) {
        int q = qw + g * 4 + r;
        float a = s0[r] * scale; if (k0 + ln > q)      a = -1e30f;
        float b = s1[r] * scale; if (k0 + 16 + ln > q) b = -1e30f;
        float mx = fmaxf(a, b);
        mx = fmaxf(mx, __shfl_xor(mx, 1));
        mx = fmaxf(mx, __shfl_xor(mx, 2));
        mx = fmaxf(mx, __shfl_xor(mx, 4));
        mx = fmaxf(mx, __shfl_xor(mx, 8));
        float mn = fmaxf(m_run[r], mx);
        float pa = __expf(a - mn), pb = __expf(b - mn);
        float cs = __expf(m_run[r] - mn);
        float rs = pa + pb;
        rs += __shfl_xor(rs, 1);
        rs += __shfl_xor(rs, 2);
        rs += __shfl_xor(rs, 4);
        rs += __shfl_xor(rs, 8);
        l_run[r] = l_run[r] * cs + rs;
        m_run[r] = mn;
        cfac[r]  = cs;
        Pw[(g * 4 + r) * P_STR + ln]      = (__bf16)pa;
        Pw[(g * 4 + r) * P_STR + 16 + ln] = (__bf16)pb;
      }
      bf16x8 pfrag = *(const bf16x8*)(Pw + ln * P_STR + g * 8);
      #pragma unroll
      for (int t = 0; t < 4; t++) {
        bf16x8 vf = *(const bf16x8*)(Vth + (16 * t + ln) * VT_STR + g * 8);
        f32x4 o = oacc[t];
        o[0] *= cfac[0]; o[1] *= cfac[1]; o[2] *= cfac[2]; o[3] *= cfac[3];
        oacc[t] = MFMA16(pfrag, vf, o);
      }
    }
  }

  float inv[4];
  #pragma unroll
  for (int r = 0; r < 4; r++) inv[r] = 1.f / l_run[r];
  #pragma unroll
  for (int t = 0; t < 4; t++)
    #pragma unroll
    for (int r = 0; r < 4; r++) {
      int q = qw + g * 4 + r;
      ao[(size_t)(bb * T_ + q) * DM + h * DH + 16 * t + ln] =
          (__bf16)(oacc[t][r] * inv[r]);
    }
}

// ---------------------------------------------------------------------------
extern "C" void kernel_launch(void* const* d_in, const int* in_sizes, int n_in,
                              void* d_out, int out_size, void* d_ws, size_t ws_size,
                              hipStream_t stream) {
  const float* x     = (const float*)d_in[0];
  const float* w_dq  = (const float*)d_in[1];
  const float* w_uq  = (const float*)d_in[2];
  const float* w_rq  = (const float*)d_in[3];
  const float* w_dkv = (const float*)d_in[4];
  const float* w_rk  = (const float*)d_in[5];
  const float* w_uk  = (const float*)d_in[6];
  const float* w_uv  = (const float*)d_in[7];
  const float* w_o   = (const float*)d_in[8];
  float* out = (float*)d_out;

  __bf16* p = (__bf16*)d_ws;
  __bf16* xb   = p;                        p += (size_t)BT * DM;        // 4096x1024
  __bf16* B1t  = p;                        p += (size_t)672 * 1024;     // [672][1024]
  __bf16* B2t  = p;                        p += (size_t)1536 * 384;     // [1536][384]
  __bf16* B3t  = p;                        p += (size_t)2048 * 256;     // [2048][256]
  __bf16* B4t  = p;                        p += (size_t)1024 * 1024;    // [1024][1024]
  __bf16* cqkr = p;                        p += (size_t)BT * 672;       // c_q|c_kv|kr
  __bf16* qsqr = p;                        p += (size_t)BT * 1536;      // qs|qr
  __bf16* kv   = p;                        p += (size_t)BT * 2048;      // ks|vs
  __bf16* qb   = p;                        p += (size_t)B_ * NH * T_ * DQK;
  __bf16* kb   = p;                        p += (size_t)B_ * NH * T_ * DQK;
  __bf16* vb   = p;                        p += (size_t)B_ * NH * T_ * DH;
  __bf16* aob  = xb;   // xb dead after G1

  dim3 tblk(32, 8);
  // Prep: cast x, cast+transpose+concat weights
  cast_f32_bf16<<<(BT * DM) / 1024, 256, 0, stream>>>(x, xb);
  transpose_cast<<<dim3(1024/32, 384/32), tblk, 0, stream>>>(w_dq,  B1t,              1024, 384);
  transpose_cast<<<dim3(1024/32, 256/32), tblk, 0, stream>>>(w_dkv, B1t + 384*1024,   1024, 256);
  transpose_cast<<<dim3(1024/32, 32/32),  tblk, 0, stream>>>(w_rk,  B1t + 640*1024,   1024, 32);
  transpose_cast<<<dim3(384/32, 1024/32), tblk, 0, stream>>>(w_uq,  B2t,              384, 1024);
  transpose_cast<<<dim3(384/32, 512/32),  tblk, 0, stream>>>(w_rq,  B2t + 1024*384,   384, 512);
  transpose_cast<<<dim3(256/32, 1024/32), tblk, 0, stream>>>(w_uk,  B3t,              256, 1024);
  transpose_cast<<<dim3(256/32, 1024/32), tblk, 0, stream>>>(w_uv,  B3t + 1024*256,   256, 1024);
  transpose_cast<<<dim3(1024/32, 1024/32),tblk, 0, stream>>>(w_o,   B4t,              1024, 1024);

  // Fused projections (bf16 MFMA)
  gemm_mfma<__bf16><<<dim3(6,  BT/128), 256, 0, stream>>>(xb,   DM,  B1t, 1024, 672,  cqkr, 672,  1024);
  gemm_mfma<__bf16><<<dim3(12, BT/128), 256, 0, stream>>>(cqkr, 672, B2t, 384,  1536, qsqr, 1536, 384);
  gemm_mfma<__bf16><<<dim3(16, BT/128), 256, 0, stream>>>(cqkr + 384, 672, B3t, 256, 2048, kv, 2048, 256);

  // RoPE + concat + RMS-norm + head-major bf16 layouts
  assemble_qk<<<(BT * NH) / 4, 256, 0, stream>>>(qsqr, kv, cqkr, qb, kb, vb);

  // Causal MFMA flash attention -> bf16 ao
  flash_mfma<<<dim3(T_ / 64, B_ * NH), 256, 0, stream>>>(qb, kb, vb, aob);

  // Output projection (fp32 out)
  gemm_mfma<float><<<dim3(8, BT/128), 256, 0, stream>>>(aob, DM, B4t, 1024, 1024, out, DM, 1024);
}

// Round 4
// 311.354 us; speedup vs baseline: 6.8987x; 1.3113x over previous
//
#include <hip/hip_runtime.h>
#include <cstdint>
#include <cstddef>
#include <math.h>

#define B_   2
#define T_   2048
#define DM   1024
#define NH   16
#define DH   64
#define DC1  384
#define DCC  256
#define DR   32
#define BT   (B_*T_)
#define DQK  96      // DH + DR

typedef __bf16 bf16x8 __attribute__((ext_vector_type(8)));
typedef __bf16 bf16x4 __attribute__((ext_vector_type(4)));
typedef float  f32x4  __attribute__((ext_vector_type(4)));
#define MFMA16(a,b,c) __builtin_amdgcn_mfma_f32_16x16x32_bf16((a),(b),(c),0,0,0)

__device__ __forceinline__ void gld16(const __bf16* g, __bf16* l) {
  __builtin_amdgcn_global_load_lds(
      (const __attribute__((address_space(1))) void*)g,
      (__attribute__((address_space(3))) void*)l, 16, 0, 0);
}

// ---------------------------------------------------------------------------
// bf16 MFMA GEMM: C[M,N] = A[M,K] @ Bt[N,K]^T.  (m97 structure, unchanged)
// ---------------------------------------------------------------------------
template<typename CT>
__global__ __launch_bounds__(256) void gemm_mfma(
    const __bf16* __restrict__ A, int lda,
    const __bf16* __restrict__ Bt, int ldb, int Nvalid,
    CT* __restrict__ C, int ldc, int K) {
  __shared__ __align__(16) __bf16 As[128 * 32];
  __shared__ __align__(16) __bf16 Bs[128 * 32];
  const int m0 = blockIdx.y * 128, n0 = blockIdx.x * 128;
  const int tid = threadIdx.x;
  const int w = tid >> 6, l = tid & 63;
  const int g = l >> 4, ln = l & 15;
  const int wm = w >> 1, wn = w & 1;

  const int slot0 = (w * 2 + 0) * 64 + l;
  const int slot1 = (w * 2 + 1) * 64 + l;
  const __bf16* ga0 = A + (size_t)(m0 + (slot0 >> 2)) * lda + (slot0 & 3) * 8;
  const __bf16* ga1 = A + (size_t)(m0 + (slot1 >> 2)) * lda + (slot1 & 3) * 8;
  int bn0 = n0 + (slot0 >> 2); if (bn0 >= Nvalid) bn0 = Nvalid - 1;
  int bn1 = n0 + (slot1 >> 2); if (bn1 >= Nvalid) bn1 = Nvalid - 1;
  const __bf16* gb0 = Bt + (size_t)bn0 * ldb + (slot0 & 3) * 8;
  const __bf16* gb1 = Bt + (size_t)bn1 * ldb + (slot1 & 3) * 8;
  __bf16* la0 = As + (w * 2 + 0) * 512;
  __bf16* la1 = As + (w * 2 + 1) * 512;
  __bf16* lb0 = Bs + (w * 2 + 0) * 512;
  __bf16* lb1 = Bs + (w * 2 + 1) * 512;

  f32x4 acc[4][4];
  #pragma unroll
  for (int i = 0; i < 4; i++)
    #pragma unroll
    for (int j = 0; j < 4; j++) acc[i][j] = (f32x4){0.f, 0.f, 0.f, 0.f};

  for (int k0 = 0; k0 < K; k0 += 32) {
    gld16(ga0 + k0, la0);
    gld16(ga1 + k0, la1);
    gld16(gb0 + k0, lb0);
    gld16(gb1 + k0, lb1);
    __syncthreads();
    bf16x8 af[4], bfr[4];
    #pragma unroll
    for (int mt = 0; mt < 4; mt++)
      af[mt] = *(const bf16x8*)(As + (wm * 64 + mt * 16 + ln) * 32 + g * 8);
    #pragma unroll
    for (int nt = 0; nt < 4; nt++)
      bfr[nt] = *(const bf16x8*)(Bs + (wn * 64 + nt * 16 + ln) * 32 + g * 8);
    #pragma unroll
    for (int mt = 0; mt < 4; mt++)
      #pragma unroll
      for (int nt = 0; nt < 4; nt++)
        acc[mt][nt] = MFMA16(af[mt], bfr[nt], acc[mt][nt]);
    __syncthreads();
  }

  #pragma unroll
  for (int mt = 0; mt < 4; mt++)
    #pragma unroll
    for (int r = 0; r < 4; r++) {
      int m = m0 + wm * 64 + mt * 16 + g * 4 + r;
      #pragma unroll
      for (int nt = 0; nt < 4; nt++) {
        int n = n0 + wn * 64 + nt * 16 + ln;
        if (n < Nvalid) C[(size_t)m * ldc + n] = (CT)acc[mt][nt][r];
      }
    }
}

// ---------------------------------------------------------------------------
// Fused weight prep: 8 matrices fp32 [K,N] -> bf16 transposed [N,K].
// ---------------------------------------------------------------------------
struct TDescs {
  const float* src[8];
  __bf16* dst[8];
  int K[8];
  int N[8];
  int t0[9];   // cumulative tile starts, t0[8] = total tiles
};

__global__ __launch_bounds__(256) void transpose_cast_all(TDescs td) {
  __shared__ float t[32][33];
  int bx = blockIdx.x;
  int i = 7;
  while (bx < td.t0[i]) i--;
  int local = bx - td.t0[i];
  int ntn = td.N[i] >> 5;
  int kt = local / ntn;
  int nt = local - kt * ntn;
  const int ks = kt * 32, ns = nt * 32;
  const float* src = td.src[i];
  __bf16* dst = td.dst[i];
  const int K = td.K[i], N = td.N[i];
  const int tx = threadIdx.x, ty = threadIdx.y;
  #pragma unroll
  for (int r = 0; r < 4; r++)
    t[ty + r * 8][tx] = src[(size_t)(ks + ty + r * 8) * N + ns + tx];
  __syncthreads();
  #pragma unroll
  for (int r = 0; r < 4; r++)
    dst[(size_t)(ns + ty + r * 8) * K + ks + tx] = (__bf16)t[tx][ty + r * 8];
}

__global__ __launch_bounds__(256) void cast_f32_bf16(
    const float* __restrict__ src, __bf16* __restrict__ dst) {
  int i = (blockIdx.x * 256 + threadIdx.x) * 4;
  float4 v = *(const float4*)(src + i);
  bf16x4 o = { (__bf16)v.x, (__bf16)v.y, (__bf16)v.z, (__bf16)v.w };
  *(bf16x4*)(dst + i) = o;
}

// ---------------------------------------------------------------------------
// Assemble: per (row, head) wave -> RoPE + concat + RMS-norm.
// qb/kb [(b*16+h)][t][96] bf16. (V handled by the V^T GEMM, not here.)
// ---------------------------------------------------------------------------
__global__ __launch_bounds__(256) void assemble_qk(
    const __bf16* __restrict__ qsqr,  // [BT][1536]: qs | qr
    const __bf16* __restrict__ kv,    // [BT][1024]: ks
    const __bf16* __restrict__ cqkr,  // [BT][672]: kr at cols 640..671
    __bf16* __restrict__ qb, __bf16* __restrict__ kb) {
  int wid  = (blockIdx.x * blockDim.x + threadIdx.x) >> 6;
  int lane = threadIdx.x & 63;
  int h   = wid & (NH - 1);
  int row = wid >> 4;
  int b   = row >> 11;
  int t   = row & (T_ - 1);

  float v0q = (float)qsqr[(size_t)row * 1536 + h * DH + lane];
  float v0k = (float)kv[(size_t)row * 1024 + h * DH + lane];
  float v1q = 0.f, v1k = 0.f;
  if (lane < DR) {
    int j  = lane;
    int jj = j & 15;
    float invf = powf(10000.f, -(float)jj / 16.f);
    float ang  = (float)t * invf;
    float s, c;
    sincosf(ang, &s, &c);
    float qx1 = (float)qsqr[(size_t)row * 1536 + 1024 + h * DR + jj];
    float qx2 = (float)qsqr[(size_t)row * 1536 + 1024 + h * DR + 16 + jj];
    float kx1 = (float)cqkr[(size_t)row * 672 + 640 + jj];
    float kx2 = (float)cqkr[(size_t)row * 672 + 640 + 16 + jj];
    if (j < 16) { v1q = qx1 * c - qx2 * s; v1k = kx1 * c - kx2 * s; }
    else        { v1q = qx1 * s + qx2 * c; v1k = kx1 * s + kx2 * c; }
  }
  float ssq = v0q * v0q + v1q * v1q;
  float ssk = v0k * v0k + v1k * v1k;
  #pragma unroll
  for (int off = 32; off; off >>= 1) {
    ssq += __shfl_xor(ssq, off);
    ssk += __shfl_xor(ssk, off);
  }
  float sq = rsqrtf(ssq / 96.f + 1e-6f);
  float sk = rsqrtf(ssk / 96.f + 1e-6f);
  size_t obase = ((size_t)(b * NH + h) * T_ + t) * DQK;
  qb[obase + lane] = (__bf16)(v0q * sq);
  kb[obase + lane] = (__bf16)(v0k * sk);
  if (lane < DR) {
    qb[obase + DH + lane] = (__bf16)(v1q * sq);
    kb[obase + DH + lane] = (__bf16)(v1k * sk);
  }
}

// ---------------------------------------------------------------------------
// Fixed-max MFMA flash attention (causal).
// RMS-normed q,k => |score| <= sqrt(96): exp() needs NO running max, so no
// cross-lane reductions, no rescale. Row-sum l via ones-row appended to V^T.
// Block = 128 queries (4 waves x 32q), K-tile = 64 keys.
// Grid: (16 q-tiles heavy-first, 32 hb).
// ---------------------------------------------------------------------------
#define KS_STR 104   // K LDS row stride: 208 B -> 2-way per 16-lane phase
#define VT_STR 72    // V^T / P row stride: 144 B -> 2-way
__global__ __launch_bounds__(256) void flash_mfma(
    const __bf16* __restrict__ qg, const __bf16* __restrict__ kg,
    const __bf16* __restrict__ vt,  // [b*1024 + h*64 + d][T_]  (V^T)
    __bf16* __restrict__ ao) {
  __shared__ __align__(16) __bf16 Ksh[64 * KS_STR];
  __shared__ __align__(16) __bf16 Vth[80 * VT_STR];
  __shared__ __align__(16) __bf16 Psh[4 * 32 * VT_STR];

  const int hb = blockIdx.y;
  const int bb = hb >> 4, h = hb & 15;
  const int q0 = T_ - 128 - 128 * blockIdx.x;   // heavy tiles first
  const int w    = threadIdx.x >> 6;
  const int lane = threadIdx.x & 63;
  const int g    = lane >> 4;
  const int ln   = lane & 15;
  const int qw = q0 + w * 32;
  const float scale = 0.10206207261596577f;  // 1/sqrt(96)
  const size_t hbT = (size_t)hb * T_;
  const __bf16* vrow = vt + (size_t)(bb * 1024 + h * 64) * T_;

  // ones row (d=64) for the l-sum column; rows 65..79 zero. Written once.
  for (int i = threadIdx.x; i < 16 * VT_STR; i += 256)
    Vth[64 * VT_STR + i] = (i < VT_STR) ? (__bf16)1.0f : (__bf16)0.0f;

  bf16x8 qfrag[2][3];
  #pragma unroll
  for (int mt = 0; mt < 2; mt++)
    #pragma unroll
    for (int s = 0; s < 3; s++)
      qfrag[mt][s] = *(const bf16x8*)(qg + (hbT + qw + mt * 16 + ln) * DQK + s * 32 + g * 8);

  f32x4 oacc[2][5];
  #pragma unroll
  for (int mt = 0; mt < 2; mt++)
    #pragma unroll
    for (int nt = 0; nt < 5; nt++) oacc[mt][nt] = (f32x4){0.f, 0.f, 0.f, 0.f};

  __bf16* Pw = Psh + w * 32 * VT_STR;
  const int kmax = q0 + 128;

  for (int k0 = 0; k0 < kmax; k0 += 64) {
    __syncthreads();
    // stage K tile [64 keys][96 dims]
    #pragma unroll
    for (int it = 0; it < 3; it++) {
      int slot = threadIdx.x + it * 256;
      int row = slot / 12, col = slot % 12;
      bf16x8 kvv = *(const bf16x8*)(kg + (hbT + k0 + row) * DQK + col * 8);
      *(bf16x8*)(Ksh + row * KS_STR + col * 8) = kvv;
    }
    // stage V^T tile [64 dims][64 keys] — already transposed in global
    #pragma unroll
    for (int it = 0; it < 2; it++) {
      int slot = threadIdx.x + it * 256;
      int row = slot >> 3, col = slot & 7;
      bf16x8 vv = *(const bf16x8*)(vrow + (size_t)row * T_ + k0 + col * 8);
      *(bf16x8*)(Vth + row * VT_STR + col * 8) = vv;
    }
    __syncthreads();

    if (k0 <= qw + 31) {          // wave-uniform skip of fully-masked tiles
      // S = Q K^T  (32q x 64k per wave)
      f32x4 saf[2][4];
      #pragma unroll
      for (int mt = 0; mt < 2; mt++)
        #pragma unroll
        for (int ks = 0; ks < 4; ks++) saf[mt][ks] = (f32x4){0.f, 0.f, 0.f, 0.f};
      #pragma unroll
      for (int s = 0; s < 3; s++)
        #pragma unroll
        for (int ks = 0; ks < 4; ks++) {
          bf16x8 kf = *(const bf16x8*)(Ksh + (ks * 16 + ln) * KS_STR + s * 32 + g * 8);
          saf[0][ks] = MFMA16(qfrag[0][s], kf, saf[0][ks]);
          saf[1][ks] = MFMA16(qfrag[1][s], kf, saf[1][ks]);
        }
      // p = exp(s*scale), mask only on diagonal tiles, store P (bf16)
      const bool diag = (k0 + 63 > qw);
      #pragma unroll
      for (int mt = 0; mt < 2; mt++)
        #pragma unroll
        for (int ks = 0; ks < 4; ks++)
          #pragma unroll
          for (int r = 0; r < 4; r++) {
            float p = __expf(saf[mt][ks][r] * scale);
            if (diag) {
              int q   = qw + mt * 16 + g * 4 + r;
              int key = k0 + ks * 16 + ln;
              if (key > q) p = 0.f;
            }
            Pw[(mt * 16 + g * 4 + r) * VT_STR + ks * 16 + ln] = (__bf16)p;
          }
      // O += P V^T  (5th n-tile = l-sum column)
      #pragma unroll
      for (int ks2 = 0; ks2 < 2; ks2++) {
        bf16x8 pf0 = *(const bf16x8*)(Pw + (ln) * VT_STR + ks2 * 32 + g * 8);
        bf16x8 pf1 = *(const bf16x8*)(Pw + (16 + ln) * VT_STR + ks2 * 32 + g * 8);
        #pragma unroll
        for (int nt = 0; nt < 5; nt++) {
          bf16x8 vf = *(const bf16x8*)(Vth + (nt * 16 + ln) * VT_STR + ks2 * 32 + g * 8);
          oacc[0][nt] = MFMA16(pf0, vf, oacc[0][nt]);
          oacc[1][nt] = MFMA16(pf1, vf, oacc[1][nt]);
        }
      }
    }
  }

  // l lives in the sum column (d=64 -> nt=4, ln=0); broadcast within group
  float linv[2][4];
  #pragma unroll
  for (int mt = 0; mt < 2; mt++)
    #pragma unroll
    for (int r = 0; r < 4; r++)
      linv[mt][r] = 1.0f / __shfl(oacc[mt][4][r], lane & 48);

  #pragma unroll
  for (int mt = 0; mt < 2; mt++)
    #pragma unroll
    for (int nt = 0; nt < 4; nt++)
      #pragma unroll
      for (int r = 0; r < 4; r++) {
        int q = qw + mt * 16 + g * 4 + r;
        ao[(size_t)(bb * T_ + q) * DM + h * DH + nt * 16 + ln] =
            (__bf16)(oacc[mt][nt][r] * linv[mt][r]);
      }
}

// ---------------------------------------------------------------------------
extern "C" void kernel_launch(void* const* d_in, const int* in_sizes, int n_in,
                              void* d_out, int out_size, void* d_ws, size_t ws_size,
                              hipStream_t stream) {
  const float* x     = (const float*)d_in[0];
  const float* w_dq  = (const float*)d_in[1];
  const float* w_uq  = (const float*)d_in[2];
  const float* w_rq  = (const float*)d_in[3];
  const float* w_dkv = (const float*)d_in[4];
  const float* w_rk  = (const float*)d_in[5];
  const float* w_uk  = (const float*)d_in[6];
  const float* w_uv  = (const float*)d_in[7];
  const float* w_o   = (const float*)d_in[8];
  float* out = (float*)d_out;

  __bf16* p = (__bf16*)d_ws;
  __bf16* xb   = p;  p += (size_t)BT * DM;
  __bf16* B1t  = p;  p += (size_t)672 * 1024;
  __bf16* B2t  = p;  p += (size_t)1536 * 384;
  __bf16* B3t  = p;  p += (size_t)2048 * 256;   // w_uk^T | w_uv^T
  __bf16* B4t  = p;  p += (size_t)1024 * 1024;
  __bf16* cqkr = p;  p += (size_t)BT * 672;     // c_q | c_kv | kr
  __bf16* qsqr = p;  p += (size_t)BT * 1536;    // qs | qr
  __bf16* kv   = p;  p += (size_t)BT * 1024;    // ks
  __bf16* vt   = p;  p += (size_t)BT * 1024;    // V^T [b*1024+h*64+d][T]
  __bf16* qb   = p;  p += (size_t)B_ * NH * T_ * DQK;
  __bf16* kb   = p;  p += (size_t)B_ * NH * T_ * DQK;
  __bf16* aob  = xb;   // xb dead after G1

  // Prep: cast x; fused transpose of all 8 weights
  cast_f32_bf16<<<(BT * DM) / 1024, 256, 0, stream>>>(x, xb);
  {
    TDescs td;
    const float* srcs[8] = {w_dq, w_dkv, w_rk, w_uq, w_rq, w_uk, w_uv, w_o};
    __bf16* dsts[8] = {B1t, B1t + (size_t)384 * 1024, B1t + (size_t)640 * 1024,
                       B2t, B2t + (size_t)1024 * 384,
                       B3t, B3t + (size_t)1024 * 256, B4t};
    int Ks[8] = {1024, 1024, 1024, 384, 384, 256, 256, 1024};
    int Ns[8] = {384, 256, 32, 1024, 512, 1024, 1024, 1024};
    int acc = 0;
    for (int i = 0; i < 8; i++) {
      td.src[i] = srcs[i]; td.dst[i] = dsts[i];
      td.K[i] = Ks[i]; td.N[i] = Ns[i];
      td.t0[i] = acc;
      acc += (Ks[i] / 32) * (Ns[i] / 32);
    }
    td.t0[8] = acc;
    transpose_cast_all<<<acc, dim3(32, 8), 0, stream>>>(td);
  }

  // Projections (bf16 MFMA)
  gemm_mfma<__bf16><<<dim3(6,  BT/128), 256, 0, stream>>>(xb,   DM,  B1t, 1024, 672,  cqkr, 672,  1024);
  gemm_mfma<__bf16><<<dim3(12, BT/128), 256, 0, stream>>>(cqkr, 672, B2t, 384,  1536, qsqr, 1536, 384);
  gemm_mfma<__bf16><<<dim3(8,  BT/128), 256, 0, stream>>>(cqkr + 384, 672, B3t, 256, 1024, kv, 1024, 256);
  // V^T = w_uv^T @ c_kv^T, per batch — operands already in the right layouts
  for (int b = 0; b < B_; b++)
    gemm_mfma<__bf16><<<dim3(16, 8), 256, 0, stream>>>(
        B3t + (size_t)1024 * 256, 256,
        cqkr + (size_t)b * T_ * 672 + 384, 672, T_,
        vt + (size_t)b * 1024 * T_, T_, 256);

  // RoPE + concat + RMS-norm
  assemble_qk<<<(BT * NH) / 4, 256, 0, stream>>>(qsqr, kv, cqkr, qb, kb);

  // Fixed-max causal MFMA flash attention -> bf16 ao
  flash_mfma<<<dim3(T_ / 128, B_ * NH), 256, 0, stream>>>(qb, kb, vt, aob);

  // Output projection (fp32 out)
  gemm_mfma<float><<<dim3(8, BT/128), 256, 0, stream>>>(aob, DM, B4t, 1024, 1024, out, DM, 1024);
}

// Round 5
// 281.048 us; speedup vs baseline: 7.6426x; 1.1078x over previous
//
#include <hip/hip_runtime.h>
#include <cstdint>
#include <cstddef>
#include <math.h>

#define B_   2
#define T_   2048
#define DM   1024
#define NH   16
#define DH   64
#define DC1  384
#define DCC  256
#define DR   32
#define BT   (B_*T_)
#define DQK  96      // DH + DR

typedef __bf16 bf16x8 __attribute__((ext_vector_type(8)));
typedef __bf16 bf16x4 __attribute__((ext_vector_type(4)));
typedef float  f32x4  __attribute__((ext_vector_type(4)));
#define MFMA16(a,b,c) __builtin_amdgcn_mfma_f32_16x16x32_bf16((a),(b),(c),0,0,0)

__device__ __forceinline__ void gld16(const __bf16* g, __bf16* l) {
  __builtin_amdgcn_global_load_lds(
      (const __attribute__((address_space(1))) void*)g,
      (__attribute__((address_space(3))) void*)l, 16, 0, 0);
}

// ---------------------------------------------------------------------------
// Multi-GEMM, single-barrier double-buffered gld16 pipeline.
// Each desc: C[M,N] = A[M,K] @ Bt[N,K]^T, 128x128 tile, BK=32.
// Grid is 1-D; block -> desc via blk0 table, then (bx,by) within desc.
// ---------------------------------------------------------------------------
struct GemmDesc {
  const __bf16* A;
  const __bf16* Bt;
  void* C;
  int lda, ldb, ldc, K, Nvalid, ntx, blk0;
};
struct GemmBatch { GemmDesc d[4]; int nd; };

template<typename CT>
__global__ __launch_bounds__(256) void gemm_multi(GemmBatch gb) {
  __shared__ __align__(16) __bf16 As[2][128 * 32];
  __shared__ __align__(16) __bf16 Bs[2][128 * 32];
  const int bid = blockIdx.x;
  int di = gb.nd - 1;
  while (di > 0 && bid < gb.d[di].blk0) di--;
  const GemmDesc D = gb.d[di];
  const int local = bid - D.blk0;
  const int by = local / D.ntx, bx = local - by * D.ntx;
  const int m0 = by * 128, n0 = bx * 128;

  const int tid = threadIdx.x;
  const int w = tid >> 6, l = tid & 63;
  const int g = l >> 4, ln = l & 15;
  const int wm = w >> 1, wn = w & 1;

  // staging slots: wave w covers slots [w*128, w*128+128), 16B each
  const int slot0 = w * 128 + l;
  const int slot1 = w * 128 + 64 + l;
  const __bf16* ga0 = D.A + (size_t)(m0 + (slot0 >> 2)) * D.lda + (slot0 & 3) * 8;
  const __bf16* ga1 = D.A + (size_t)(m0 + (slot1 >> 2)) * D.lda + (slot1 & 3) * 8;
  int bn0 = n0 + (slot0 >> 2); if (bn0 >= D.Nvalid) bn0 = D.Nvalid - 1;
  int bn1 = n0 + (slot1 >> 2); if (bn1 >= D.Nvalid) bn1 = D.Nvalid - 1;
  const __bf16* gb0 = D.Bt + (size_t)bn0 * D.ldb + (slot0 & 3) * 8;
  const __bf16* gb1 = D.Bt + (size_t)bn1 * D.ldb + (slot1 & 3) * 8;

  f32x4 acc[4][4];
  #pragma unroll
  for (int i = 0; i < 4; i++)
    #pragma unroll
    for (int j = 0; j < 4; j++) acc[i][j] = (f32x4){0.f, 0.f, 0.f, 0.f};

  // prime buffer 0
  {
    __bf16* a_dst = As[0] + w * 1024;
    __bf16* b_dst = Bs[0] + w * 1024;
    gld16(ga0, a_dst);
    gld16(ga1, a_dst + 512);
    gld16(gb0, b_dst);
    gld16(gb1, b_dst + 512);
  }

  const int niter = D.K >> 5;
  int p = 0;
  for (int it = 0; it < niter; ++it) {
    __syncthreads();            // drains vmcnt -> buf[p] ready
    if (it + 1 < niter) {       // prefetch next tile into buf[p^1]
      const int ko = (it + 1) * 32;
      __bf16* a_dst = As[p ^ 1] + w * 1024;
      __bf16* b_dst = Bs[p ^ 1] + w * 1024;
      gld16(ga0 + ko, a_dst);
      gld16(ga1 + ko, a_dst + 512);
      gld16(gb0 + ko, b_dst);
      gld16(gb1 + ko, b_dst + 512);
    }
    bf16x8 af[4], bfr[4];
    #pragma unroll
    for (int mt = 0; mt < 4; mt++)
      af[mt] = *(const bf16x8*)(As[p] + (wm * 64 + mt * 16 + ln) * 32 + g * 8);
    #pragma unroll
    for (int nt = 0; nt < 4; nt++)
      bfr[nt] = *(const bf16x8*)(Bs[p] + (wn * 64 + nt * 16 + ln) * 32 + g * 8);
    #pragma unroll
    for (int mt = 0; mt < 4; mt++)
      #pragma unroll
      for (int nt = 0; nt < 4; nt++)
        acc[mt][nt] = MFMA16(af[mt], bfr[nt], acc[mt][nt]);
    p ^= 1;
  }

  CT* C = (CT*)D.C;
  #pragma unroll
  for (int mt = 0; mt < 4; mt++)
    #pragma unroll
    for (int r = 0; r < 4; r++) {
      int m = m0 + wm * 64 + mt * 16 + g * 4 + r;
      #pragma unroll
      for (int nt = 0; nt < 4; nt++) {
        int n = n0 + wn * 64 + nt * 16 + ln;
        if (n < D.Nvalid) C[(size_t)m * D.ldc + n] = (CT)acc[mt][nt][r];
      }
    }
}

// ---------------------------------------------------------------------------
// Fused weight prep: 8 matrices fp32 [K,N] -> bf16 transposed [N,K].
// ---------------------------------------------------------------------------
struct TDescs {
  const float* src[8];
  __bf16* dst[8];
  int K[8];
  int N[8];
  int t0[9];
};

__global__ __launch_bounds__(256) void transpose_cast_all(TDescs td) {
  __shared__ float t[32][33];
  int bx = blockIdx.x;
  int i = 7;
  while (bx < td.t0[i]) i--;
  int local = bx - td.t0[i];
  int ntn = td.N[i] >> 5;
  int kt = local / ntn;
  int nt = local - kt * ntn;
  const int ks = kt * 32, ns = nt * 32;
  const float* src = td.src[i];
  __bf16* dst = td.dst[i];
  const int K = td.K[i], N = td.N[i];
  const int tx = threadIdx.x, ty = threadIdx.y;
  #pragma unroll
  for (int r = 0; r < 4; r++)
    t[ty + r * 8][tx] = src[(size_t)(ks + ty + r * 8) * N + ns + tx];
  __syncthreads();
  #pragma unroll
  for (int r = 0; r < 4; r++)
    dst[(size_t)(ns + ty + r * 8) * K + ks + tx] = (__bf16)t[tx][ty + r * 8];
  (void)K;
}

__global__ __launch_bounds__(256) void cast_f32_bf16(
    const float* __restrict__ src, __bf16* __restrict__ dst) {
  int i = (blockIdx.x * 256 + threadIdx.x) * 4;
  float4 v = *(const float4*)(src + i);
  bf16x4 o = { (__bf16)v.x, (__bf16)v.y, (__bf16)v.z, (__bf16)v.w };
  *(bf16x4*)(dst + i) = o;
}

// ---------------------------------------------------------------------------
// Assemble: per (row, head) wave -> RoPE + concat + RMS-norm.
// ---------------------------------------------------------------------------
__global__ __launch_bounds__(256) void assemble_qk(
    const __bf16* __restrict__ qsqr,  // [BT][1536]: qs | qr
    const __bf16* __restrict__ kv,    // [BT][1024]: ks
    const __bf16* __restrict__ cqkr,  // [BT][672]: kr at cols 640..671
    __bf16* __restrict__ qb, __bf16* __restrict__ kb) {
  int wid  = (blockIdx.x * blockDim.x + threadIdx.x) >> 6;
  int lane = threadIdx.x & 63;
  int h   = wid & (NH - 1);
  int row = wid >> 4;
  int b   = row >> 11;
  int t   = row & (T_ - 1);

  float v0q = (float)qsqr[(size_t)row * 1536 + h * DH + lane];
  float v0k = (float)kv[(size_t)row * 1024 + h * DH + lane];
  float v1q = 0.f, v1k = 0.f;
  if (lane < DR) {
    int j  = lane;
    int jj = j & 15;
    float invf = powf(10000.f, -(float)jj / 16.f);
    float ang  = (float)t * invf;
    float s, c;
    sincosf(ang, &s, &c);
    float qx1 = (float)qsqr[(size_t)row * 1536 + 1024 + h * DR + jj];
    float qx2 = (float)qsqr[(size_t)row * 1536 + 1024 + h * DR + 16 + jj];
    float kx1 = (float)cqkr[(size_t)row * 672 + 640 + jj];
    float kx2 = (float)cqkr[(size_t)row * 672 + 640 + 16 + jj];
    if (j < 16) { v1q = qx1 * c - qx2 * s; v1k = kx1 * c - kx2 * s; }
    else        { v1q = qx1 * s + qx2 * c; v1k = kx1 * s + kx2 * c; }
  }
  float ssq = v0q * v0q + v1q * v1q;
  float ssk = v0k * v0k + v1k * v1k;
  #pragma unroll
  for (int off = 32; off; off >>= 1) {
    ssq += __shfl_xor(ssq, off);
    ssk += __shfl_xor(ssk, off);
  }
  float sq = rsqrtf(ssq / 96.f + 1e-6f);
  float sk = rsqrtf(ssk / 96.f + 1e-6f);
  size_t obase = ((size_t)(b * NH + h) * T_ + t) * DQK;
  qb[obase + lane] = (__bf16)(v0q * sq);
  kb[obase + lane] = (__bf16)(v0k * sk);
  if (lane < DR) {
    qb[obase + DH + lane] = (__bf16)(v1q * sq);
    kb[obase + DH + lane] = (__bf16)(v1k * sk);
  }
}

// ---------------------------------------------------------------------------
// Fixed-max MFMA flash attention (causal), register-prefetched staging.
// |score| <= sqrt(96) (RMS-normed q,k) => plain exp, no running max.
// Denominator accumulated in registers; 4 shuffles at the end.
// Block = 128 queries (4 waves x 32q), K-tile = 64 keys. LDS = 40 KB.
// ---------------------------------------------------------------------------
#define KS_STR 104   // K LDS row stride
#define VT_STR 72    // V^T / P row stride
__global__ __launch_bounds__(256) void flash_mfma(
    const __bf16* __restrict__ qg, const __bf16* __restrict__ kg,
    const __bf16* __restrict__ vt,  // [b*1024 + h*64 + d][T_]  (V^T)
    __bf16* __restrict__ ao) {
  __shared__ __align__(16) __bf16 Ksh[64 * KS_STR];   // 13312 B
  __shared__ __align__(16) __bf16 Vth[64 * VT_STR];   //  9216 B
  __shared__ __align__(16) __bf16 Psh[4 * 32 * VT_STR]; // 18432 B

  const int hb = blockIdx.y;
  const int bb = hb >> 4, h = hb & 15;
  const int q0 = T_ - 128 - 128 * blockIdx.x;   // heavy tiles first
  const int w    = threadIdx.x >> 6;
  const int lane = threadIdx.x & 63;
  const int g    = lane >> 4;
  const int ln   = lane & 15;
  const int qw = q0 + w * 32;
  const float scale = 0.10206207261596577f;  // 1/sqrt(96)
  const size_t hbT = (size_t)hb * T_;
  const __bf16* vrow = vt + (size_t)(bb * 1024 + h * 64) * T_;

  // staging slot coords (constant per thread)
  int krow[3], kcol[3], vr[2], vc[2];
  #pragma unroll
  for (int it = 0; it < 3; it++) {
    int slot = threadIdx.x + it * 256;
    krow[it] = slot / 12; kcol[it] = slot % 12;
  }
  #pragma unroll
  for (int it = 0; it < 2; it++) {
    int slot = threadIdx.x + it * 256;
    vr[it] = slot >> 3; vc[it] = slot & 7;
  }

  bf16x8 qfrag[2][3];
  #pragma unroll
  for (int mt = 0; mt < 2; mt++)
    #pragma unroll
    for (int s = 0; s < 3; s++)
      qfrag[mt][s] = *(const bf16x8*)(qg + (hbT + qw + mt * 16 + ln) * DQK + s * 32 + g * 8);

  f32x4 oacc[2][4];
  #pragma unroll
  for (int mt = 0; mt < 2; mt++)
    #pragma unroll
    for (int nt = 0; nt < 4; nt++) oacc[mt][nt] = (f32x4){0.f, 0.f, 0.f, 0.f};
  float lsum[2][4] = {};

  __bf16* Pw = Psh + w * 32 * VT_STR;
  const int kmax = q0 + 128;

  bf16x8 kreg[3], vreg[2];
  #pragma unroll
  for (int it = 0; it < 3; it++)
    kreg[it] = *(const bf16x8*)(kg + (hbT + krow[it]) * DQK + kcol[it] * 8);
  #pragma unroll
  for (int it = 0; it < 2; it++)
    vreg[it] = *(const bf16x8*)(vrow + (size_t)vr[it] * T_ + vc[it] * 8);

  for (int k0 = 0; k0 < kmax; k0 += 64) {
    __syncthreads();   // previous compute done reading Ksh/Vth
    #pragma unroll
    for (int it = 0; it < 3; it++)
      *(bf16x8*)(Ksh + krow[it] * KS_STR + kcol[it] * 8) = kreg[it];
    #pragma unroll
    for (int it = 0; it < 2; it++)
      *(bf16x8*)(Vth + vr[it] * VT_STR + vc[it] * 8) = vreg[it];
    __syncthreads();
    if (k0 + 64 < kmax) {   // prefetch next tile into regs (hidden by compute)
      #pragma unroll
      for (int it = 0; it < 3; it++)
        kreg[it] = *(const bf16x8*)(kg + (hbT + k0 + 64 + krow[it]) * DQK + kcol[it] * 8);
      #pragma unroll
      for (int it = 0; it < 2; it++)
        vreg[it] = *(const bf16x8*)(vrow + (size_t)vr[it] * T_ + k0 + 64 + vc[it] * 8);
    }

    if (k0 <= qw + 31) {          // wave-uniform skip of fully-masked tiles
      // S = Q K^T  (32q x 64k per wave)
      f32x4 saf[2][4];
      #pragma unroll
      for (int mt = 0; mt < 2; mt++)
        #pragma unroll
        for (int ks = 0; ks < 4; ks++) saf[mt][ks] = (f32x4){0.f, 0.f, 0.f, 0.f};
      #pragma unroll
      for (int s = 0; s < 3; s++)
        #pragma unroll
        for (int ks = 0; ks < 4; ks++) {
          bf16x8 kf = *(const bf16x8*)(Ksh + (ks * 16 + ln) * KS_STR + s * 32 + g * 8);
          saf[0][ks] = MFMA16(qfrag[0][s], kf, saf[0][ks]);
          saf[1][ks] = MFMA16(qfrag[1][s], kf, saf[1][ks]);
        }
      // p = exp(s*scale); mask on diagonal tiles; accumulate l; store P
      const bool diag = (k0 + 63 > qw);
      #pragma unroll
      for (int mt = 0; mt < 2; mt++)
        #pragma unroll
        for (int ks = 0; ks < 4; ks++)
          #pragma unroll
          for (int r = 0; r < 4; r++) {
            float p = __expf(saf[mt][ks][r] * scale);
            if (diag) {
              int q   = qw + mt * 16 + g * 4 + r;
              int key = k0 + ks * 16 + ln;
              if (key > q) p = 0.f;
            }
            lsum[mt][r] += p;
            Pw[(mt * 16 + g * 4 + r) * VT_STR + ks * 16 + ln] = (__bf16)p;
          }
      // O += P V^T
      #pragma unroll
      for (int ks2 = 0; ks2 < 2; ks2++) {
        bf16x8 pf0 = *(const bf16x8*)(Pw + (ln) * VT_STR + ks2 * 32 + g * 8);
        bf16x8 pf1 = *(const bf16x8*)(Pw + (16 + ln) * VT_STR + ks2 * 32 + g * 8);
        #pragma unroll
        for (int nt = 0; nt < 4; nt++) {
          bf16x8 vf = *(const bf16x8*)(Vth + (nt * 16 + ln) * VT_STR + ks2 * 32 + g * 8);
          oacc[0][nt] = MFMA16(pf0, vf, oacc[0][nt]);
          oacc[1][nt] = MFMA16(pf1, vf, oacc[1][nt]);
        }
      }
    }
  }

  // reduce l across the 16 ln-lanes (g bits untouched by xor 1/2/4/8)
  float linv[2][4];
  #pragma unroll
  for (int mt = 0; mt < 2; mt++)
    #pragma unroll
    for (int r = 0; r < 4; r++) {
      float s = lsum[mt][r];
      s += __shfl_xor(s, 1);
      s += __shfl_xor(s, 2);
      s += __shfl_xor(s, 4);
      s += __shfl_xor(s, 8);
      linv[mt][r] = 1.0f / s;
    }

  #pragma unroll
  for (int mt = 0; mt < 2; mt++)
    #pragma unroll
    for (int nt = 0; nt < 4; nt++)
      #pragma unroll
      for (int r = 0; r < 4; r++) {
        int q = qw + mt * 16 + g * 4 + r;
        ao[(size_t)(bb * T_ + q) * DM + h * DH + nt * 16 + ln] =
            (__bf16)(oacc[mt][nt][r] * linv[mt][r]);
      }
}

// ---------------------------------------------------------------------------
extern "C" void kernel_launch(void* const* d_in, const int* in_sizes, int n_in,
                              void* d_out, int out_size, void* d_ws, size_t ws_size,
                              hipStream_t stream) {
  const float* x     = (const float*)d_in[0];
  const float* w_dq  = (const float*)d_in[1];
  const float* w_uq  = (const float*)d_in[2];
  const float* w_rq  = (const float*)d_in[3];
  const float* w_dkv = (const float*)d_in[4];
  const float* w_rk  = (const float*)d_in[5];
  const float* w_uk  = (const float*)d_in[6];
  const float* w_uv  = (const float*)d_in[7];
  const float* w_o   = (const float*)d_in[8];
  float* out = (float*)d_out;

  __bf16* p = (__bf16*)d_ws;
  __bf16* xb   = p;  p += (size_t)BT * DM;
  __bf16* B1t  = p;  p += (size_t)672 * 1024;
  __bf16* B2t  = p;  p += (size_t)1536 * 384;
  __bf16* B3t  = p;  p += (size_t)2048 * 256;   // w_uk^T | w_uv^T
  __bf16* B4t  = p;  p += (size_t)1024 * 1024;
  __bf16* cqkr = p;  p += (size_t)BT * 672;     // c_q | c_kv | kr
  __bf16* qsqr = p;  p += (size_t)BT * 1536;    // qs | qr
  __bf16* kv   = p;  p += (size_t)BT * 1024;    // ks
  __bf16* vt   = p;  p += (size_t)BT * 1024;    // V^T [b*1024+h*64+d][T]
  __bf16* qb   = p;  p += (size_t)B_ * NH * T_ * DQK;
  __bf16* kb   = p;  p += (size_t)B_ * NH * T_ * DQK;
  __bf16* aob  = xb;   // xb dead after G1

  // Prep: cast x; fused transpose of all 8 weights
  cast_f32_bf16<<<(BT * DM) / 1024, 256, 0, stream>>>(x, xb);
  {
    TDescs td;
    const float* srcs[8] = {w_dq, w_dkv, w_rk, w_uq, w_rq, w_uk, w_uv, w_o};
    __bf16* dsts[8] = {B1t, B1t + (size_t)384 * 1024, B1t + (size_t)640 * 1024,
                       B2t, B2t + (size_t)1024 * 384,
                       B3t, B3t + (size_t)1024 * 256, B4t};
    int Ks[8] = {1024, 1024, 1024, 384, 384, 256, 256, 1024};
    int Ns[8] = {384, 256, 32, 1024, 512, 1024, 1024, 1024};
    int acc = 0;
    for (int i = 0; i < 8; i++) {
      td.src[i] = srcs[i]; td.dst[i] = dsts[i];
      td.K[i] = Ks[i]; td.N[i] = Ns[i];
      td.t0[i] = acc;
      acc += (Ks[i] / 32) * (Ns[i] / 32);
    }
    td.t0[8] = acc;
    transpose_cast_all<<<acc, dim3(32, 8), 0, stream>>>(td);
  }

  // G1: cqkr = xb @ B1t^T   (192 blocks)
  {
    GemmBatch g; g.nd = 1;
    g.d[0] = GemmDesc{xb, B1t, (void*)cqkr, DM, 1024, 672, 1024, 672, 6, 0};
    gemm_multi<__bf16><<<192, 256, 0, stream>>>(g);
  }
  // Fused: G2 (qsqr), G3 (ks), VT batch 0, VT batch 1   (896 blocks)
  {
    GemmBatch g; g.nd = 4;
    g.d[0] = GemmDesc{cqkr, B2t, (void*)qsqr, 672, 384, 1536, 384, 1536, 12, 0};
    g.d[1] = GemmDesc{cqkr + 384, B3t, (void*)kv, 672, 256, 1024, 256, 1024, 8, 384};
    g.d[2] = GemmDesc{B3t + (size_t)1024 * 256, cqkr + 384, (void*)vt,
                      256, 672, T_, 256, T_, 16, 640};
    g.d[3] = GemmDesc{B3t + (size_t)1024 * 256, cqkr + (size_t)T_ * 672 + 384,
                      (void*)(vt + (size_t)1024 * T_), 256, 672, T_, 256, T_, 16, 768};
    gemm_multi<__bf16><<<896, 256, 0, stream>>>(g);
  }

  // RoPE + concat + RMS-norm
  assemble_qk<<<(BT * NH) / 4, 256, 0, stream>>>(qsqr, kv, cqkr, qb, kb);

  // Fixed-max causal MFMA flash attention -> bf16 ao
  flash_mfma<<<dim3(T_ / 128, B_ * NH), 256, 0, stream>>>(qb, kb, vt, aob);

  // G4: out = aob @ B4t^T  (fp32 out, 256 blocks)
  {
    GemmBatch g; g.nd = 1;
    g.d[0] = GemmDesc{aob, B4t, (void*)out, DM, 1024, DM, 1024, 1024, 8, 0};
    gemm_multi<float><<<256, 256, 0, stream>>>(g);
  }
}